// Round 2
// baseline (532.925 us; speedup 1.0000x reference)
//
#include <hip/hip_runtime.h>
#include <hip/hip_bf16.h>
#include <math.h>

typedef __hip_bfloat16 bf16;
typedef __bf16 bf8v __attribute__((ext_vector_type(8)));
typedef float f4v __attribute__((ext_vector_type(4)));

__device__ inline void storeC(bf16* p, float v) { *p = __float2bfloat16(v); }
__device__ inline void storeC(float* p, float v) { *p = v; }

// async global->LDS, 16B per lane; LDS base must be wave-uniform, HW adds lane*16.
__device__ inline void gld16(const void* g, void* l) {
    __builtin_amdgcn_global_load_lds(
        (__attribute__((address_space(1))) void*)g,
        (__attribute__((address_space(3))) void*)l, 16, 0, 0);
}

// ---------------- fp32 -> bf16 cast (vectorized, n % 1024 == 0) ----------------
__global__ __launch_bounds__(256)
void cast_f2b(const float* __restrict__ X, bf16* __restrict__ Y, long n)
{
    const long i = ((long)blockIdx.x * 256 + threadIdx.x) * 4;
    if (i + 3 < n) {
        const float4 v = *(const float4*)(X + i);
        Y[i + 0] = __float2bfloat16(v.x);
        Y[i + 1] = __float2bfloat16(v.y);
        Y[i + 2] = __float2bfloat16(v.z);
        Y[i + 3] = __float2bfloat16(v.w);
    }
}

// ---------------- GEMM 256xBN tile, ring-4 K-slot pipeline ----------------
// C[M,N] = epi( A[M,K] @ W[N,K]^T + bias[N] ), A,W bf16; bias,R fp32.
// 512 threads = 8 waves (2M x 4N), per-wave C = 128 x (BN/4).
// BK=32; LDS ring of 4 slots (each A[256][32] + B[BN][32] bf16), stage 3 tiles
// ahead via global_load_lds (linear lane-contiguous dest, pre-swizzled global
// source so LDS holds chunk c at position c ^ ((row>>2)&3) -> conflict-free
// ds_read_b128). Counted vmcnt: steady state 2 tiles in flight behind the one
// being consumed; never vmcnt(0) until the final tile.
// WAR safety: stage(t+3) writes slot (t+3)&3 == (t-1)&3, whose last ds_reads
// were consumed by MFMA before this wave reached the tile-t barrier, and the
// stage is issued after that barrier (sched_barrier pins it).
template<int ACT, bool HASRES, typename CT, int K, int BN>
__global__ __launch_bounds__(512, 2)
void gemm256(const bf16* __restrict__ A, const bf16* __restrict__ W,
             const float* __restrict__ bias, const float* __restrict__ Rr,
             CT* __restrict__ C, int N)
{
    extern __shared__ __align__(16) unsigned short lds[];
    constexpr int NT   = K / 32;         // K-tiles
    constexpr int NREP = BN / 64;        // B fragments per wave (4 or 2)
    constexpr int A_SH = 256 * 32;       // shorts per A slot (16 KB)
    constexpr int SLOT = A_SH + BN * 32; // shorts per ring slot

    // XCD-aware bijective block swizzle (all grids here have nwg % 8 == 0)
    int id = blockIdx.y * gridDim.x + blockIdx.x;
    const int nwg = gridDim.x * gridDim.y;
    id = (id & 7) * (nwg >> 3) + (id >> 3);
    const int bm = id % gridDim.x;
    const int bn = id / gridDim.x;
    const long row0 = (long)bm * 256;
    const long col0 = (long)bn * BN;

    const int tid  = threadIdx.x;
    const int lane = tid & 63;
    const int wave = tid >> 6;
    const int wm = wave >> 2;            // 0..1 -> 128-row strip
    const int wn = wave & 3;             // 0..3 -> (BN/4)-col strip
    const int fr = lane & 15;            // fragment row/col
    // swizzled k-chunk (shorts): chunk (lane>>4) XOR row-selector ((fr>>2)&3)
    const int ksw = (((lane >> 4) ^ ((lane >> 2) & 3)) << 3);

    // staging: thread t owns (row = t>>2, chunk = t&3) of a 128-row block;
    // source chunk pre-swizzled so LDS[row][c] = global[row][c ^ ((row>>2)&3)].
    const int srow = tid >> 2;
    const int csrc = (tid & 3) ^ ((srow >> 2) & 3);
    const unsigned short* gA = (const unsigned short*)A + (row0 + srow) * (long)K + csrc * 8;
    const unsigned short* gB = (const unsigned short*)W + (col0 + srow) * (long)K + csrc * 8;
    unsigned short* const wbase = lds + wave * 512;   // wave-uniform LDS base part

    auto stage = [&](int t) {
        const long k0 = (long)t * 32;
        unsigned short* sl = wbase + (t & 3) * SLOT;
        gld16(gA + k0,                 sl);           // A rows 0-127
        gld16(gA + 128 * (long)K + k0, sl + 4096);    // A rows 128-255
        gld16(gB + k0,                 sl + A_SH);    // B rows 0-127
        if constexpr (BN == 256)
            gld16(gB + 128 * (long)K + k0, sl + A_SH + 4096);  // B rows 128-255
    };

    f4v acc[8][NREP];
#pragma unroll
    for (int i = 0; i < 8; ++i)
#pragma unroll
        for (int j = 0; j < NREP; ++j) acc[i][j] = {0.f, 0.f, 0.f, 0.f};

    // prologue: tiles 0,1,2 -> slots 0,1,2
    stage(0); stage(1); stage(2);

#pragma unroll 4
    for (int t = 0; t < NT; ++t) {
        // own tile-t loads landed (2 tiles allowed in flight behind; tail drains)
        if constexpr (BN == 256) {
            if (t + 2 < NT)      asm volatile("s_waitcnt vmcnt(8)" ::: "memory");
            else if (t + 1 < NT) asm volatile("s_waitcnt vmcnt(4)" ::: "memory");
            else                 asm volatile("s_waitcnt vmcnt(0)" ::: "memory");
        } else {
            if (t + 2 < NT)      asm volatile("s_waitcnt vmcnt(6)" ::: "memory");
            else if (t + 1 < NT) asm volatile("s_waitcnt vmcnt(3)" ::: "memory");
            else                 asm volatile("s_waitcnt vmcnt(0)" ::: "memory");
        }
        __builtin_amdgcn_s_barrier();           // all waves' tile-t data in LDS
        __builtin_amdgcn_sched_barrier(0);      // pin: nothing floats above barrier
        if (t + 3 < NT) stage(t + 3);           // -> slot last read at tile t-1

        const unsigned short* sA = lds + (t & 3) * SLOT;
        const unsigned short* sB = sA + A_SH;

        bf8v bfrag[NREP];
#pragma unroll
        for (int ni = 0; ni < NREP; ++ni)
            bfrag[ni] = *(const bf8v*)&sB[(wn * (NREP * 16) + ni * 16 + fr) * 32 + ksw];

#pragma unroll
        for (int ph = 0; ph < 2; ++ph) {
            bf8v afrag[4];
#pragma unroll
            for (int mi = 0; mi < 4; ++mi)
                afrag[mi] = *(const bf8v*)&sA[(wm * 128 + ph * 64 + mi * 16 + fr) * 32 + ksw];
            __builtin_amdgcn_s_setprio(1);
#pragma unroll
            for (int mi = 0; mi < 4; ++mi)
#pragma unroll
                for (int ni = 0; ni < NREP; ++ni)
                    acc[ph * 4 + mi][ni] = __builtin_amdgcn_mfma_f32_16x16x32_bf16(
                        afrag[mi], bfrag[ni], acc[ph * 4 + mi][ni], 0, 0, 0);
            __builtin_amdgcn_s_setprio(0);
        }
    }
    // fence: keep epilogue global loads from being hoisted into the counted-vmcnt loop
    __builtin_amdgcn_sched_barrier(0);

    // epilogue: D mapping col = lane&15 (via B row), row = (lane>>4)*4 + reg
#pragma unroll
    for (int ni = 0; ni < NREP; ++ni) {
        const long n = col0 + wn * (NREP * 16) + ni * 16 + fr;
        const float bvv = bias[n];
#pragma unroll
        for (int mi = 0; mi < 8; ++mi) {
            const long mbase = row0 + wm * 128 + mi * 16 + (lane >> 4) * 4;
#pragma unroll
            for (int r = 0; r < 4; ++r) {
                float v0 = acc[mi][ni][r] + bvv;
                if (HASRES) v0 += Rr[(mbase + r) * (long)N + n];
                if (ACT == 1) v0 = 0.5f * v0 * (1.f + erff(v0 * 0.70710678118654752f));
                storeC(&C[(mbase + r) * (long)N + n], v0);
            }
        }
    }
}

// ---------------- per-position head attention (the einsum quirk) ----------------
__global__ __launch_bounds__(256)
void attn_kernel(const bf16* __restrict__ qkv, bf16* __restrict__ scr)
{
    __shared__ float sb[4][3392];   // per wave: q[16][65], k[16][65], v[16][65], a[16][17]
    const int tid = threadIdx.x;
    const int wave = tid >> 6, lane = tid & 63;
    const int m = blockIdx.x * 4 + wave;       // global position in [0, 8192)

    float* q = sb[wave];
    float* k = q + 1040;
    float* v = k + 1040;
    float* a = v + 1040;

    const bf16* rowp = qkv + (size_t)m * 3072;
    for (int i = lane; i < 1024; i += 64) {
        int hh = i >> 6, dd = i & 63;
        q[hh * 65 + dd] = __bfloat162float(rowp[i]);
        k[hh * 65 + dd] = __bfloat162float(rowp[1024 + i]);
        v[hh * 65 + dd] = __bfloat162float(rowp[2048 + i]);
    }
    __syncthreads();

    const int h1 = lane & 15, qd = lane >> 4;
    float e[4];
#pragma unroll
    for (int j = 0; j < 4; ++j) {
        const float* qr = q + h1 * 65;
        const float* kr = k + (qd * 4 + j) * 65;
        float s0 = 0.f;
        for (int d = 0; d < 64; ++d) s0 += qr[d] * kr[d];
        e[j] = s0 * 0.03125f;                  // 1/sqrt(1024)
    }
    float mx = fmaxf(fmaxf(e[0], e[1]), fmaxf(e[2], e[3]));
    mx = fmaxf(mx, __shfl_xor(mx, 16, 64));
    mx = fmaxf(mx, __shfl_xor(mx, 32, 64));
    float p[4], ps = 0.f;
#pragma unroll
    for (int j = 0; j < 4; ++j) { p[j] = expf(e[j] - mx); ps += p[j]; }
    ps += __shfl_xor(ps, 16, 64);
    ps += __shfl_xor(ps, 32, 64);
    const float inv = 1.f / ps;
#pragma unroll
    for (int j = 0; j < 4; ++j) a[h1 * 17 + qd * 4 + j] = p[j] * inv;
    __syncthreads();

    const int h = lane & 15, dg = lane >> 4;
    float arow[16];
#pragma unroll
    for (int l2 = 0; l2 < 16; ++l2) arow[l2] = a[h * 17 + l2];
    const int b = m >> 11, j = m & 2047;
    bf16* op = scr + (((size_t)b * 2048 + h * 128 + (j >> 4)) * 1024 + (j & 15) * 64);
    for (int t = 0; t < 16; ++t) {
        const int d = dg * 16 + t;
        float o = 0.f;
#pragma unroll
        for (int l2 = 0; l2 < 16; ++l2) o += arow[l2] * v[l2 * 65 + d];
        op[d] = __float2bfloat16(o);
    }
}

// -------- row LayerNorm over E=1024, fp32 in, fp32 out (+optional bf16 copy) --------
__global__ __launch_bounds__(256)
void ln_kernel(const float* __restrict__ X, const float* __restrict__ G,
               const float* __restrict__ Bt, float* __restrict__ Y32,
               bf16* __restrict__ Yb)
{
    __shared__ float rs[4], rq[4];
    const int tid = threadIdx.x;
    const long row = blockIdx.x;
    const float* xp = X + row * 1024;
    float x[4];
#pragma unroll
    for (int i = 0; i < 4; ++i) x[i] = xp[tid + 256 * i];

    float s = x[0] + x[1] + x[2] + x[3];
#pragma unroll
    for (int off = 32; off; off >>= 1) s += __shfl_down(s, off, 64);
    if ((tid & 63) == 0) rs[tid >> 6] = s;
    __syncthreads();
    const float mean = (rs[0] + rs[1] + rs[2] + rs[3]) * (1.f / 1024.f);

    float qv = 0.f;
#pragma unroll
    for (int i = 0; i < 4; ++i) { float d = x[i] - mean; qv += d * d; }
#pragma unroll
    for (int off = 32; off; off >>= 1) qv += __shfl_down(qv, off, 64);
    if ((tid & 63) == 0) rq[tid >> 6] = qv;
    __syncthreads();
    const float var = (rq[0] + rq[1] + rq[2] + rq[3]) * (1.f / 1024.f);
    const float rstd = rsqrtf(var + 1e-5f);

#pragma unroll
    for (int i = 0; i < 4; ++i) {
        const int e = tid + 256 * i;
        const float yv = (x[i] - mean) * rstd * G[e] + Bt[e];
        Y32[row * 1024 + e] = yv;
        if (Yb) Yb[row * 1024 + e] = __float2bfloat16(yv);
    }
}

extern "C" void kernel_launch(void* const* d_in, const int* in_sizes, int n_in,
                              void* d_out, int out_size, void* d_ws, size_t ws_size,
                              hipStream_t stream)
{
    (void)in_sizes; (void)n_in; (void)out_size;
    const float* x    = (const float*)d_in[0];
    const float* Wqkv = (const float*)d_in[1];
    const float* bqkv = (const float*)d_in[2];
    const float* Wo   = (const float*)d_in[3];
    const float* bo   = (const float*)d_in[4];
    const float* g1   = (const float*)d_in[5];
    const float* b1   = (const float*)d_in[6];
    const float* W1   = (const float*)d_in[7];
    const float* bf1  = (const float*)d_in[8];
    const float* W2   = (const float*)d_in[9];
    const float* bf2  = (const float*)d_in[10];
    const float* g2   = (const float*)d_in[11];
    const float* b2   = (const float*)d_in[12];
    float* out = (float*)d_out;

    if (ws_size < 125829120ULL) return;

    // ws layout (bytes):
    //   R1 @0, 67,108,864: qkv bf16(50.3M) -> t fp32(33.5M) -> u bf16(67M)
    //   Wqkvb @67108864 (6.3M) | Wob @73400320 (2.1M) | W1b @75497472 (8.4M)
    //   W2b @83886080 (8.4M)   | xb/scr @92274688 (16.8M) | hb @109051904 (16.8M)
    char* ws = (char*)d_ws;
    bf16* qkv   = (bf16*)(ws + 0);
    float* t    = (float*)(ws + 0);
    bf16* u     = (bf16*)(ws + 0);
    bf16* Wqkvb = (bf16*)(ws + 67108864);
    bf16* Wob   = (bf16*)(ws + 73400320);
    bf16* W1b   = (bf16*)(ws + 75497472);
    bf16* W2b   = (bf16*)(ws + 83886080);
    bf16* xb    = (bf16*)(ws + 92274688);
    bf16* scr   = (bf16*)(ws + 92274688);   // reuses xb (dead after gemm1)
    bf16* hb    = (bf16*)(ws + 109051904);
    float* h    = out;                       // fp32 h lives in d_out until gemm6

    // 0) casts fp32 -> bf16
    cast_f2b<<<8192, 256, 0, stream>>>(x,    xb,    8388608);
    cast_f2b<<<3072, 256, 0, stream>>>(Wqkv, Wqkvb, 3145728);
    cast_f2b<<<1024, 256, 0, stream>>>(Wo,   Wob,   1048576);
    cast_f2b<<<4096, 256, 0, stream>>>(W1,   W1b,   4194304);
    cast_f2b<<<4096, 256, 0, stream>>>(W2,   W2b,   4194304);

    // 1) qkv = x @ Wqkv^T + bqkv            (bf16 out)   grid 32x12 = 384 wg
    gemm256<0, false, bf16, 1024, 256><<<dim3(32, 12), 512, 131072, stream>>>(xb, Wqkvb, bqkv, nullptr, qkv, 3072);
    // 2) per-position head attention + reshape scramble -> scr
    attn_kernel<<<2048, 256, 0, stream>>>(qkv, scr);
    // 3) t = scr @ Wo^T + bo + x            (fp32 out, fp32 residual)  grid 256 wg
    gemm256<0, true, float, 1024, 128><<<dim3(32, 8), 512, 98304, stream>>>(scr, Wob, bo, x, t, 1024);
    // 4) h = LN1(t)  -> fp32 h (d_out) + bf16 hb
    ln_kernel<<<8192, 256, 0, stream>>>(t, g1, b1, h, hb);
    // 5) u = gelu(hb @ W1^T + bf1)          (bf16 out)   grid 32x16 = 512 wg
    gemm256<1, false, bf16, 1024, 256><<<dim3(32, 16), 512, 131072, stream>>>(hb, W1b, bf1, nullptr, u, 4096);
    // 6) s2 = u @ W2^T + bf2 + h            (fp32 out aliasing R=h elementwise)  grid 256 wg
    gemm256<0, true, float, 4096, 128><<<dim3(32, 8), 512, 98304, stream>>>(u, W2b, bf2, h, out, 1024);
    // 7) out = LN2(s2) in-place, fp32 only
    ln_kernel<<<8192, 256, 0, stream>>>(out, g2, b2, out, nullptr);
}

// Round 3
// 470.959 us; speedup vs baseline: 1.1316x; 1.1316x over previous
//
#include <hip/hip_runtime.h>
#include <hip/hip_bf16.h>
#include <math.h>

typedef __hip_bfloat16 bf16;
typedef __bf16 bf8v __attribute__((ext_vector_type(8)));
typedef float f4v __attribute__((ext_vector_type(4)));

__device__ inline float gelu_act(float v) {
    return 0.5f * v * (1.f + erff(v * 0.70710678118654752f));
}

// async global->LDS, 16B per lane; LDS base must be wave-uniform, HW adds lane*16.
__device__ inline void gld16(const void* g, void* l) {
    __builtin_amdgcn_global_load_lds(
        (__attribute__((address_space(1))) void*)g,
        (__attribute__((address_space(3))) void*)l, 16, 0, 0);
}

// ---------------- fp32 -> bf16 cast (vectorized, n % 1024 == 0) ----------------
__global__ __launch_bounds__(256)
void cast_f2b(const float* __restrict__ X, bf16* __restrict__ Y, long n)
{
    const long i = ((long)blockIdx.x * 256 + threadIdx.x) * 4;
    if (i + 3 < n) {
        const float4 v = *(const float4*)(X + i);
        Y[i + 0] = __float2bfloat16(v.x);
        Y[i + 1] = __float2bfloat16(v.y);
        Y[i + 2] = __float2bfloat16(v.z);
        Y[i + 3] = __float2bfloat16(v.w);
    }
}

// ---------------- GEMM 256xBN tile, ring-4 K-slot pipeline ----------------
// C[M,N] = epi( A[M,K] @ W[N,K]^T + bias[N] ), A,W bf16; bias,R fp32.
// 512 threads = 8 waves (2M x 4N), per-wave C = 128 x (BN/4).
// K-loop: BK=32, LDS ring of 4 slots, 3 tiles prefetched via global_load_lds,
// counted vmcnt (never 0 mid-loop), raw s_barrier, XOR-swizzled conflict-free
// ds_read_b128, s_setprio around the MFMA cluster.  [round-2 verified]
// Epilogue (new): stage acc as f32 in LDS (ring is dead), read back row-major,
// apply bias/residual/gelu with float4 loads, store full-line float4/ushort4.
// Fixes 2.4x write amplification + write-allocate fetches of the scalar-store
// epilogue (round-2 counters: WRITE 161.6MB vs 67MB ideal on FFN1).
template<int ACT, bool HASRES, typename CT, int K, int BN>
__global__ __launch_bounds__(512, 2)
void gemm256(const bf16* __restrict__ A, const bf16* __restrict__ W,
             const float* __restrict__ bias, const float* __restrict__ Rr,
             CT* __restrict__ C, int N)
{
    extern __shared__ __align__(16) unsigned short lds[];
    constexpr int NT   = K / 32;         // K-tiles
    constexpr int NREP = BN / 64;        // B fragments per wave (4 or 2)
    constexpr int A_SH = 256 * 32;       // shorts per A slot (16 KB)
    constexpr int SLOT = A_SH + BN * 32; // shorts per ring slot

    // XCD supertile swizzle: XCD x owns bm in {4x..4x+3} x all bn, so the 32
    // concurrent blocks/XCD share 4 A-strips + 8 B-strips in its private L2.
    // Requires gridDim.x == 32 and nwg % 8 == 0 (true for all four GEMMs).
    const int o     = blockIdx.y * gridDim.x + blockIdx.x;
    const int local = o >> 3;
    const int bm = (o & 7) * 4 + (local & 3);
    const int bn = local >> 2;
    const long row0 = (long)bm * 256;
    const long col0 = (long)bn * BN;

    const int tid  = threadIdx.x;
    const int lane = tid & 63;
    const int wave = tid >> 6;
    const int wm = wave >> 2;            // 0..1 -> 128-row strip
    const int wn = wave & 3;             // 0..3 -> (BN/4)-col strip
    const int fr = lane & 15;            // fragment row/col
    // swizzled k-chunk (shorts): chunk (lane>>4) XOR row-selector ((fr>>2)&3)
    const int ksw = (((lane >> 4) ^ ((lane >> 2) & 3)) << 3);

    // staging: thread t owns (row = t>>2, chunk = t&3) of a 128-row block;
    // source chunk pre-swizzled so LDS[row][c] = global[row][c ^ ((row>>2)&3)].
    const int srow = tid >> 2;
    const int csrc = (tid & 3) ^ ((srow >> 2) & 3);
    const unsigned short* gA = (const unsigned short*)A + (row0 + srow) * (long)K + csrc * 8;
    const unsigned short* gB = (const unsigned short*)W + (col0 + srow) * (long)K + csrc * 8;
    unsigned short* const wbase = lds + wave * 512;   // wave-uniform LDS base part

    auto stage = [&](int t) {
        const long k0 = (long)t * 32;
        unsigned short* sl = wbase + (t & 3) * SLOT;
        gld16(gA + k0,                 sl);           // A rows 0-127
        gld16(gA + 128 * (long)K + k0, sl + 4096);    // A rows 128-255
        gld16(gB + k0,                 sl + A_SH);    // B rows 0-127
        if constexpr (BN == 256)
            gld16(gB + 128 * (long)K + k0, sl + A_SH + 4096);  // B rows 128-255
    };

    f4v acc[8][NREP];
#pragma unroll
    for (int i = 0; i < 8; ++i)
#pragma unroll
        for (int j = 0; j < NREP; ++j) acc[i][j] = {0.f, 0.f, 0.f, 0.f};

    // prologue: tiles 0,1,2 -> slots 0,1,2
    stage(0); stage(1); stage(2);

#pragma unroll 4
    for (int t = 0; t < NT; ++t) {
        // own tile-t loads landed (2 tiles allowed in flight behind; tail drains)
        if constexpr (BN == 256) {
            if (t + 2 < NT)      asm volatile("s_waitcnt vmcnt(8)" ::: "memory");
            else if (t + 1 < NT) asm volatile("s_waitcnt vmcnt(4)" ::: "memory");
            else                 asm volatile("s_waitcnt vmcnt(0)" ::: "memory");
        } else {
            if (t + 2 < NT)      asm volatile("s_waitcnt vmcnt(6)" ::: "memory");
            else if (t + 1 < NT) asm volatile("s_waitcnt vmcnt(3)" ::: "memory");
            else                 asm volatile("s_waitcnt vmcnt(0)" ::: "memory");
        }
        __builtin_amdgcn_s_barrier();           // all waves' tile-t data in LDS
        __builtin_amdgcn_sched_barrier(0);      // pin: nothing floats above barrier
        if (t + 3 < NT) stage(t + 3);           // -> slot last read at tile t-1

        const unsigned short* sA = lds + (t & 3) * SLOT;
        const unsigned short* sB = sA + A_SH;

        bf8v bfrag[NREP];
#pragma unroll
        for (int ni = 0; ni < NREP; ++ni)
            bfrag[ni] = *(const bf8v*)&sB[(wn * (NREP * 16) + ni * 16 + fr) * 32 + ksw];

#pragma unroll
        for (int ph = 0; ph < 2; ++ph) {
            bf8v afrag[4];
#pragma unroll
            for (int mi = 0; mi < 4; ++mi)
                afrag[mi] = *(const bf8v*)&sA[(wm * 128 + ph * 64 + mi * 16 + fr) * 32 + ksw];
            __builtin_amdgcn_s_setprio(1);
#pragma unroll
            for (int mi = 0; mi < 4; ++mi)
#pragma unroll
                for (int ni = 0; ni < NREP; ++ni)
                    acc[ph * 4 + mi][ni] = __builtin_amdgcn_mfma_f32_16x16x32_bf16(
                        afrag[mi], bfrag[ni], acc[ph * 4 + mi][ni], 0, 0, 0);
            __builtin_amdgcn_s_setprio(0);
        }
    }
    // fence: keep epilogue ops from floating into the counted-vmcnt loop
    __builtin_amdgcn_sched_barrier(0);

    // ---------------- coalesced LDS-staged epilogue ----------------
    // Stage one 128-row half-tile of acc as f32 [128][STR] in the (dead) ring
    // LDS; stride STR*4 % 128 == 16 bytes -> worst case free 2-way conflicts.
    constexpr int STR = (BN == 256) ? 260 : 132;   // f32 words per staged row
    constexpr int LPR = BN / 4;                    // lanes per output row
    constexpr int RPI = 64 / LPR;                  // rows per read-iteration
    float* eb = (float*)lds;
    const int q4    = (lane >> 4) * 4;
    const int wrcol = wn * (NREP * 16) + fr;       // staged col for D-frag writes
    const int lcol  = (lane % LPR) * 4;            // read-phase col (4 per lane)
    const int lrow  = lane / LPR;                  // read-phase row sub-offset
    const long nbase = col0 + lcol;
    const float4 b4 = *(const float4*)&bias[nbase];
    const float bb[4] = {b4.x, b4.y, b4.z, b4.w};

#pragma unroll
    for (int h = 0; h < 2; ++h) {
        __syncthreads();                            // close prior LDS readers
        if (wm == h) {
#pragma unroll
            for (int mi = 0; mi < 8; ++mi)
#pragma unroll
                for (int ni = 0; ni < NREP; ++ni)
#pragma unroll
                    for (int r = 0; r < 4; ++r)
                        eb[(mi * 16 + q4 + r) * STR + wrcol + ni * 16] = acc[mi][ni][r];
        }
        __syncthreads();
#pragma unroll
        for (int i = 0; i < 16 / RPI; ++i) {
            const int  rh = wave * 16 + i * RPI + lrow;   // row within half-tile
            const long gr = row0 + h * 128 + rh;          // global output row
            const f4v v = *(const f4v*)&eb[rh * STR + lcol];
            float ov[4];
#pragma unroll
            for (int c = 0; c < 4; ++c) ov[c] = v[c] + bb[c];
            if (HASRES) {
                const float4 r4 = *(const float4*)&Rr[gr * (long)N + nbase];
                const float ra[4] = {r4.x, r4.y, r4.z, r4.w};
#pragma unroll
                for (int c = 0; c < 4; ++c) ov[c] += ra[c];
            }
            if (ACT == 1) {
#pragma unroll
                for (int c = 0; c < 4; ++c) ov[c] = gelu_act(ov[c]);
            }
            if constexpr (sizeof(CT) == 2) {
                ushort4 s;
                bf16* sp = (bf16*)&s;
#pragma unroll
                for (int c = 0; c < 4; ++c) sp[c] = __float2bfloat16(ov[c]);
                *(ushort4*)&C[gr * (long)N + nbase] = s;     // 8B, full-line
            } else {
                *(float4*)&C[gr * (long)N + nbase] = make_float4(ov[0], ov[1], ov[2], ov[3]);
            }
        }
    }
}

// ---------------- per-position head attention (the einsum quirk) ----------------
__global__ __launch_bounds__(256)
void attn_kernel(const bf16* __restrict__ qkv, bf16* __restrict__ scr)
{
    __shared__ float sb[4][3392];   // per wave: q[16][65], k[16][65], v[16][65], a[16][17]
    const int tid = threadIdx.x;
    const int wave = tid >> 6, lane = tid & 63;
    const int m = blockIdx.x * 4 + wave;       // global position in [0, 8192)

    float* q = sb[wave];
    float* k = q + 1040;
    float* v = k + 1040;
    float* a = v + 1040;

    const bf16* rowp = qkv + (size_t)m * 3072;
    for (int i = lane; i < 1024; i += 64) {
        int hh = i >> 6, dd = i & 63;
        q[hh * 65 + dd] = __bfloat162float(rowp[i]);
        k[hh * 65 + dd] = __bfloat162float(rowp[1024 + i]);
        v[hh * 65 + dd] = __bfloat162float(rowp[2048 + i]);
    }
    __syncthreads();

    const int h1 = lane & 15, qd = lane >> 4;
    float e[4];
#pragma unroll
    for (int j = 0; j < 4; ++j) {
        const float* qr = q + h1 * 65;
        const float* kr = k + (qd * 4 + j) * 65;
        float s0 = 0.f;
        for (int d = 0; d < 64; ++d) s0 += qr[d] * kr[d];
        e[j] = s0 * 0.03125f;                  // 1/sqrt(1024)
    }
    float mx = fmaxf(fmaxf(e[0], e[1]), fmaxf(e[2], e[3]));
    mx = fmaxf(mx, __shfl_xor(mx, 16, 64));
    mx = fmaxf(mx, __shfl_xor(mx, 32, 64));
    float p[4], ps = 0.f;
#pragma unroll
    for (int j = 0; j < 4; ++j) { p[j] = expf(e[j] - mx); ps += p[j]; }
    ps += __shfl_xor(ps, 16, 64);
    ps += __shfl_xor(ps, 32, 64);
    const float inv = 1.f / ps;
#pragma unroll
    for (int j = 0; j < 4; ++j) a[h1 * 17 + qd * 4 + j] = p[j] * inv;
    __syncthreads();

    const int h = lane & 15, dg = lane >> 4;
    float arow[16];
#pragma unroll
    for (int l2 = 0; l2 < 16; ++l2) arow[l2] = a[h * 17 + l2];
    const int b = m >> 11, j = m & 2047;
    bf16* op = scr + (((size_t)b * 2048 + h * 128 + (j >> 4)) * 1024 + (j & 15) * 64);
    for (int t = 0; t < 16; ++t) {
        const int d = dg * 16 + t;
        float o = 0.f;
#pragma unroll
        for (int l2 = 0; l2 < 16; ++l2) o += arow[l2] * v[l2 * 65 + d];
        op[d] = __float2bfloat16(o);
    }
}

// -------- row LayerNorm over E=1024, fp32 in, fp32 out (+optional bf16 copy) --------
__global__ __launch_bounds__(256)
void ln_kernel(const float* __restrict__ X, const float* __restrict__ G,
               const float* __restrict__ Bt, float* __restrict__ Y32,
               bf16* __restrict__ Yb)
{
    __shared__ float rs[4], rq[4];
    const int tid = threadIdx.x;
    const long row = blockIdx.x;
    const float* xp = X + row * 1024;
    float x[4];
#pragma unroll
    for (int i = 0; i < 4; ++i) x[i] = xp[tid + 256 * i];

    float s = x[0] + x[1] + x[2] + x[3];
#pragma unroll
    for (int off = 32; off; off >>= 1) s += __shfl_down(s, off, 64);
    if ((tid & 63) == 0) rs[tid >> 6] = s;
    __syncthreads();
    const float mean = (rs[0] + rs[1] + rs[2] + rs[3]) * (1.f / 1024.f);

    float qv = 0.f;
#pragma unroll
    for (int i = 0; i < 4; ++i) { float d = x[i] - mean; qv += d * d; }
#pragma unroll
    for (int off = 32; off; off >>= 1) qv += __shfl_down(qv, off, 64);
    if ((tid & 63) == 0) rq[tid >> 6] = qv;
    __syncthreads();
    const float var = (rq[0] + rq[1] + rq[2] + rq[3]) * (1.f / 1024.f);
    const float rstd = rsqrtf(var + 1e-5f);

#pragma unroll
    for (int i = 0; i < 4; ++i) {
        const int e = tid + 256 * i;
        const float yv = (x[i] - mean) * rstd * G[e] + Bt[e];
        Y32[row * 1024 + e] = yv;
        if (Yb) Yb[row * 1024 + e] = __float2bfloat16(yv);
    }
}

extern "C" void kernel_launch(void* const* d_in, const int* in_sizes, int n_in,
                              void* d_out, int out_size, void* d_ws, size_t ws_size,
                              hipStream_t stream)
{
    (void)in_sizes; (void)n_in; (void)out_size;
    const float* x    = (const float*)d_in[0];
    const float* Wqkv = (const float*)d_in[1];
    const float* bqkv = (const float*)d_in[2];
    const float* Wo   = (const float*)d_in[3];
    const float* bo   = (const float*)d_in[4];
    const float* g1   = (const float*)d_in[5];
    const float* b1   = (const float*)d_in[6];
    const float* W1   = (const float*)d_in[7];
    const float* bf1  = (const float*)d_in[8];
    const float* W2   = (const float*)d_in[9];
    const float* bf2  = (const float*)d_in[10];
    const float* g2   = (const float*)d_in[11];
    const float* b2   = (const float*)d_in[12];
    float* out = (float*)d_out;

    if (ws_size < 125829120ULL) return;

    // ws layout (bytes):
    //   R1 @0, 67,108,864: qkv bf16(50.3M) -> t fp32(33.5M) -> u bf16(67M)
    //   Wqkvb @67108864 (6.3M) | Wob @73400320 (2.1M) | W1b @75497472 (8.4M)
    //   W2b @83886080 (8.4M)   | xb/scr @92274688 (16.8M) | hb @109051904 (16.8M)
    char* ws = (char*)d_ws;
    bf16* qkv   = (bf16*)(ws + 0);
    float* t    = (float*)(ws + 0);
    bf16* u     = (bf16*)(ws + 0);
    bf16* Wqkvb = (bf16*)(ws + 67108864);
    bf16* Wob   = (bf16*)(ws + 73400320);
    bf16* W1b   = (bf16*)(ws + 75497472);
    bf16* W2b   = (bf16*)(ws + 83886080);
    bf16* xb    = (bf16*)(ws + 92274688);
    bf16* scr   = (bf16*)(ws + 92274688);   // reuses xb (dead after gemm1)
    bf16* hb    = (bf16*)(ws + 109051904);
    float* h    = out;                       // fp32 h lives in d_out until gemm6

    // dynamic LDS: ring (128K / 96K) vs f32 epilogue half-tile (133,120 / 67,584)
    constexpr unsigned LDS_BIG   = 133120;   // max(131072, 128*260*4)
    constexpr unsigned LDS_SMALL = 98304;    // max(98304, 128*132*4)

    // 0) casts fp32 -> bf16
    cast_f2b<<<8192, 256, 0, stream>>>(x,    xb,    8388608);
    cast_f2b<<<3072, 256, 0, stream>>>(Wqkv, Wqkvb, 3145728);
    cast_f2b<<<1024, 256, 0, stream>>>(Wo,   Wob,   1048576);
    cast_f2b<<<4096, 256, 0, stream>>>(W1,   W1b,   4194304);
    cast_f2b<<<4096, 256, 0, stream>>>(W2,   W2b,   4194304);

    // 1) qkv = x @ Wqkv^T + bqkv            (bf16 out)   grid 32x12 = 384 wg
    gemm256<0, false, bf16, 1024, 256><<<dim3(32, 12), 512, LDS_BIG, stream>>>(xb, Wqkvb, bqkv, nullptr, qkv, 3072);
    // 2) per-position head attention + reshape scramble -> scr
    attn_kernel<<<2048, 256, 0, stream>>>(qkv, scr);
    // 3) t = scr @ Wo^T + bo + x            (fp32 out, fp32 residual)  grid 256 wg
    gemm256<0, true, float, 1024, 128><<<dim3(32, 8), 512, LDS_SMALL, stream>>>(scr, Wob, bo, x, t, 1024);
    // 4) h = LN1(t)  -> fp32 h (d_out) + bf16 hb
    ln_kernel<<<8192, 256, 0, stream>>>(t, g1, b1, h, hb);
    // 5) u = gelu(hb @ W1^T + bf1)          (bf16 out)   grid 32x16 = 512 wg
    gemm256<1, false, bf16, 1024, 256><<<dim3(32, 16), 512, LDS_BIG, stream>>>(hb, W1b, bf1, nullptr, u, 4096);
    // 6) s2 = u @ W2^T + bf2 + h            (fp32 out aliasing R=h elementwise)  grid 256 wg
    gemm256<0, true, float, 4096, 128><<<dim3(32, 8), 512, LDS_SMALL, stream>>>(u, W2b, bf2, h, out, 1024);
    // 7) out = LN2(s2) in-place, fp32 only
    ln_kernel<<<8192, 256, 0, stream>>>(out, g2, b2, out, nullptr);
}